// Round 5
// baseline (3994.284 us; speedup 1.0000x reference)
//
#include <hip/hip_runtime.h>

#define DIN 512
#define H   1024
#define NBATCH 64
#define SEQ 512
#define M_TOTAL (NBATCH * SEQ)  // 32768

typedef float  f32x4  __attribute__((ext_vector_type(4)));
typedef __bf16 bf16x8 __attribute__((ext_vector_type(8)));
typedef short  s16x8  __attribute__((ext_vector_type(8)));
typedef short  s16x4  __attribute__((ext_vector_type(4)));

__device__ __forceinline__ unsigned short f2bf(float f) {
  unsigned u = __float_as_uint(f);
  u = (u + 0x7FFFu + ((u >> 16) & 1u)) >> 16;   // RNE truncate to bf16
  return (unsigned short)u;
}
__device__ __forceinline__ float bf2f(unsigned short h) {
  return __uint_as_float(((unsigned)h) << 16);
}
__device__ __forceinline__ f32x4 mfma_bf16(s16x8 a, s16x8 b, f32x4 c) {
  return __builtin_amdgcn_mfma_f32_16x16x32_bf16(
      __builtin_bit_cast(bf16x8, a), __builtin_bit_cast(bf16x8, b), c, 0, 0, 0);
}
// coherent (sc1) accesses: served at the MALL point, no cache-maintenance ops
__device__ __forceinline__ s16x8 ld_sc1_b128(const short* p) {
  s16x8 r;
  asm volatile("global_load_dwordx4 %0, %1, off sc1"
               : "=v"(r) : "v"(p) : "memory");
  return r;
}
__device__ __forceinline__ void st_sc1_b128(short* p, s16x8 v) {
  asm volatile("global_store_dwordx4 %0, %1, off sc1"
               :: "v"(p), "v"(v) : "memory");
}
// chunk ready = no element equals sentinel NaN 0x7FC0 (tanh data is never NaN)
__device__ __forceinline__ bool ready8(s16x8 v) {
  uint4 wv = __builtin_bit_cast(uint4, v);
  unsigned bad = 0;
  unsigned q0 = wv.x ^ 0x7FC07FC0u, q1 = wv.y ^ 0x7FC07FC0u;
  unsigned q2 = wv.z ^ 0x7FC07FC0u, q3 = wv.w ^ 0x7FC07FC0u;
  bad |= ((q0 & 0xFFFFu) == 0u) | ((q0 & 0xFFFF0000u) == 0u);
  bad |= ((q1 & 0xFFFFu) == 0u) | ((q1 & 0xFFFF0000u) == 0u);
  bad |= ((q2 & 0xFFFFu) == 0u) | ((q2 & 0xFFFF0000u) == 0u);
  bad |= ((q3 & 0xFFFFu) == 0u) | ((q3 & 0xFFFF0000u) == 0u);
  return bad == 0u;
}

// ---------------- prep: transpose + hi/lo bf16 convert --------------------
__global__ void conv_T(const float* __restrict__ in, int R, int C,
                       short* __restrict__ oh, short* __restrict__ ol) {
  int i = blockIdx.x * 256 + threadIdx.x;
  if (i >= R * C) return;
  int c = i / R, r = i - c * R;
  float v = in[r * C + c];
  unsigned short hb = f2bf(v);
  oh[i] = (short)hb;
  ol[i] = (short)f2bf(v - bf2f(hb));
}

// init h ring: buf3 = broadcast h0 (read at t=0); buf0,buf1 = sentinel NaN
// (polled at t=1,t=2 before any in-kernel clear reaches them). buf2 is
// cleared in-kernel at t=0 and first polled at t=3.
__global__ void init_h(const float* __restrict__ h0,
                       short* __restrict__ h_hi, short* __restrict__ h_lo) {
  int i = blockIdx.x * 256 + threadIdx.x;      // 0..65535
  int c = i & (H - 1);
  float v = h0[c];
  unsigned short hb = f2bf(v);
  unsigned short lb = f2bf(v - bf2f(hb));
  const int NB = NBATCH * H;
  h_hi[3 * NB + i] = (short)hb;       h_lo[3 * NB + i] = (short)lb;
  h_hi[0 * NB + i] = (short)0x7FC0;   h_lo[0 * NB + i] = (short)0x7FC0;
  h_hi[1 * NB + i] = (short)0x7FC0;   h_lo[1 * NB + i] = (short)0x7FC0;
}

// ---------------- projection GEMM: xp = x @ w_xh + b_xh + b_hh ------------
#define PBM 64
#define PBN 128
#define PBK 64
__global__ __launch_bounds__(256) void proj_kernel(
    const float* __restrict__ x,       // [M][DIN]
    const short* __restrict__ wT_hi,   // [H][DIN]
    const short* __restrict__ wT_lo,
    const float* __restrict__ b_xh,
    const float* __restrict__ b_hh,
    float* __restrict__ out) {         // [M][H] (d_out hidden region)
  __shared__ short Ahi[PBM * PBK], Alo[PBM * PBK];
  __shared__ short Bhi[PBN * PBK], Blo[PBN * PBK];
  const int n0 = blockIdx.x * PBN;
  const int m0 = blockIdx.y * PBM;
  const int tid = threadIdx.x;
  const int lane = tid & 63, w = tid >> 6;
  const int wr = w >> 1, wc = w & 1;
  const int l15 = lane & 15, kq8 = (lane >> 4) << 3;

  f32x4 acc[2][4];
#pragma unroll
  for (int a = 0; a < 2; ++a)
#pragma unroll
    for (int b = 0; b < 4; ++b) acc[a][b] = (f32x4){0.f, 0.f, 0.f, 0.f};

  for (int kc = 0; kc < DIN; kc += PBK) {
    {
      int r = tid >> 2, k0 = (tid & 3) << 4;
      const float* src = x + (size_t)(m0 + r) * DIN + kc + k0;
#pragma unroll
      for (int i = 0; i < 4; ++i) {
        float4 v = *(const float4*)(src + i * 4);
        unsigned short h0b = f2bf(v.x), h1b = f2bf(v.y), h2b = f2bf(v.z), h3b = f2bf(v.w);
        s16x4 hv = {(short)h0b, (short)h1b, (short)h2b, (short)h3b};
        s16x4 lv = {(short)f2bf(v.x - bf2f(h0b)), (short)f2bf(v.y - bf2f(h1b)),
                    (short)f2bf(v.z - bf2f(h2b)), (short)f2bf(v.w - bf2f(h3b))};
        int ad = (r * PBK + k0 + i * 4) * 2;
        ad ^= (r & 7) << 4;
        *(s16x4*)((char*)Ahi + ad) = hv;
        *(s16x4*)((char*)Alo + ad) = lv;
      }
    }
    {
      int c = tid >> 1, k0 = (tid & 1) << 5;
      const short* sh = wT_hi + (size_t)(n0 + c) * DIN + kc + k0;
      const short* sl = wT_lo + (size_t)(n0 + c) * DIN + kc + k0;
#pragma unroll
      for (int i = 0; i < 4; ++i) {
        s16x8 vh = *(const s16x8*)(sh + i * 8);
        s16x8 vl = *(const s16x8*)(sl + i * 8);
        int ad = (c * PBK + k0 + i * 8) * 2;
        ad ^= (c & 7) << 4;
        *(s16x8*)((char*)Bhi + ad) = vh;
        *(s16x8*)((char*)Blo + ad) = vl;
      }
    }
    __syncthreads();
#pragma unroll
    for (int ks = 0; ks < PBK; ks += 32) {
      s16x8 ah[2], al[2], bh[4], bl[4];
#pragma unroll
      for (int rt = 0; rt < 2; ++rt) {
        int row = wr * 32 + rt * 16 + l15;
        int ad = (row * PBK + ks + kq8) * 2;
        ad ^= (row & 7) << 4;
        ah[rt] = *(const s16x8*)((const char*)Ahi + ad);
        al[rt] = *(const s16x8*)((const char*)Alo + ad);
      }
#pragma unroll
      for (int ct = 0; ct < 4; ++ct) {
        int c = wc * 64 + ct * 16 + l15;
        int ad = (c * PBK + ks + kq8) * 2;
        ad ^= (c & 7) << 4;
        bh[ct] = *(const s16x8*)((const char*)Bhi + ad);
        bl[ct] = *(const s16x8*)((const char*)Blo + ad);
      }
#pragma unroll
      for (int rt = 0; rt < 2; ++rt)
#pragma unroll
        for (int ct = 0; ct < 4; ++ct) {
          acc[rt][ct] = mfma_bf16(ah[rt], bh[ct], acc[rt][ct]);
          acc[rt][ct] = mfma_bf16(al[rt], bh[ct], acc[rt][ct]);
          acc[rt][ct] = mfma_bf16(ah[rt], bl[ct], acc[rt][ct]);
        }
    }
    __syncthreads();
  }
#pragma unroll
  for (int rt = 0; rt < 2; ++rt)
#pragma unroll
    for (int ct = 0; ct < 4; ++ct) {
      int col = n0 + wc * 64 + ct * 16 + l15;
      float bias = b_xh[col] + b_hh[col];
#pragma unroll
      for (int i = 0; i < 4; ++i) {
        int m = m0 + wr * 32 + rt * 16 + ((lane >> 4) << 2) + i;
        out[(size_t)m * H + col] = acc[rt][ct][i] + bias;
      }
    }
}

// ---------------- persistent recurrent scan (v5: NaN-sentinel sync) -------
// 64 blocks x 256 threads. bg=bid&3 (16 rows), cg4=bid>>2 (64 cols).
// h ring: 4 bufs. Producer t writes buf[t&3] (packed 16B sc1 stores via
// per-wave LDS transpose). Consumer t polls buf[(t-1)&3] chunks until no
// element is sentinel NaN 0x7FC0 -> data IS the flag (no flags, no drain).
// After poll success, block NaN-clears its own region of buf[(t+2)&3]
// (safe: poll success proves all peers produced t-1, hence done reading
// t-2's buffer; ordering vs later data stores via staging vmcnt(0) chain).
__global__ __launch_bounds__(256, 1) void scan_kernel(
    const short* __restrict__ whT_hi,  // [H][H]
    const short* __restrict__ whT_lo,
    float* __restrict__ out,           // d_out: [64][512][1024] then [64][1024]
    short* __restrict__ h_hi,          // [4][64][1024]
    short* __restrict__ h_lo) {
  __shared__ short Hh[2][16 * H];      // 64 KB: double-buffered h tile (hi)
  __shared__ short Hl[2][16 * H];      // 64 KB: (lo)
  __shared__ unsigned TR[4][16][20];   // 5 KB: per-wave transpose scratch
  const int tid = threadIdx.x;
  const int lane = tid & 63, w = tid >> 6;
  const int bid = blockIdx.x;
  const int bg = bid & 3, cg4 = bid >> 2;
  const int l15 = lane & 15, kq = lane >> 4, kq8 = kq << 3;
  const int colbase = cg4 * 64 + w * 16;
  const int col = colbase + l15;
  const int rowbase = bg * 16;
  const int NB = NBATCH * H;

  const short NANS = (short)0x7FC0;
  const s16x8 nanvec = {NANS, NANS, NANS, NANS, NANS, NANS, NANS, NANS};

  // W hi+lo fragments in registers/AGPRs: 64 x s16x8
  s16x8 whi[32], wlo[32];
#pragma unroll
  for (int kk = 0; kk < 32; ++kk) {
    whi[kk] = *(const s16x8*)(whT_hi + (size_t)col * H + kk * 32 + kq8);
    wlo[kk] = *(const s16x8*)(whT_lo + (size_t)col * H + kk * 32 + kq8);
  }

  // per-thread staging chunk offsets (constant across steps)
  int cbase[8];
#pragma unroll
  for (int j = 0; j < 8; ++j) {
    int c = j * 256 + tid;
    cbase[j] = (rowbase + (c >> 7)) * H + ((c & 127) << 3);
  }

  // xp prefetch for t=0
  float xp[4]; unsigned offs[4];
#pragma unroll
  for (int i = 0; i < 4; ++i) {
    int b = rowbase + kq * 4 + i;
    offs[i] = ((unsigned)b * SEQ + 0) * H + col;
    xp[i] = out[offs[i]];
  }

  for (int t = 0; t < SEQ; ++t) {
    // ---- stage h(t-1) from buf[(t+3)&3] with NaN-transition poll ----
    {
      const short* ghi = h_hi + (size_t)((t + 3) & 3) * NB;
      const short* glo = h_lo + (size_t)((t + 3) & 3) * NB;
      s16x8 sh[8], sl[8];
#pragma unroll
      for (int j = 0; j < 8; ++j) {
        sh[j] = ld_sc1_b128(ghi + cbase[j]);
        sl[j] = ld_sc1_b128(glo + cbase[j]);
      }
      asm volatile("s_waitcnt vmcnt(0)" ::: "memory");
      unsigned pend = 0xFFFFu;
      int spins = 0;
      while (true) {
        unsigned np = 0;
#pragma unroll
        for (int j = 0; j < 8; ++j) {
          if ((pend >> j) & 1u)       { if (!ready8(sh[j])) np |= 1u << j; }
          if ((pend >> (j + 8)) & 1u) { if (!ready8(sl[j])) np |= 1u << (j + 8); }
        }
        pend = np;
        if (__all(pend == 0u)) break;
        if (++spins > 2048) break;   // safety: wrong answer beats a hang
#pragma unroll
        for (int j = 0; j < 8; ++j) {
          if ((pend >> j) & 1u)       sh[j] = ld_sc1_b128(ghi + cbase[j]);
          if ((pend >> (j + 8)) & 1u) sl[j] = ld_sc1_b128(glo + cbase[j]);
        }
        asm volatile("s_waitcnt vmcnt(0)" ::: "memory");
      }
      __builtin_amdgcn_sched_barrier(0);
      char* HB = (char*)&Hh[t & 1][0];
      char* LB = (char*)&Hl[t & 1][0];
#pragma unroll
      for (int j = 0; j < 8; ++j) {
        int c = j * 256 + tid;
        int ad = (c << 4) ^ (((c >> 7) & 7) << 4);   // XOR-swizzled
        *(s16x8*)(HB + ad) = sh[j];
        *(s16x8*)(LB + ad) = sl[j];
      }
    }
    __syncthreads();

    // xp prefetch for t+1 (completes under compute; next staging vmcnt waits it)
    float xpn[4] = {0.f, 0.f, 0.f, 0.f};
    unsigned offn[4] = {0u, 0u, 0u, 0u};
    if (t + 1 < SEQ) {
#pragma unroll
      for (int i = 0; i < 4; ++i) {
        int b = rowbase + kq * 4 + i;
        offn[i] = ((unsigned)b * SEQ + (t + 1)) * H + col;
        xpn[i] = out[offn[i]];
      }
    }
    // NaN-clear own region of buf[(t+2)&3] (post-poll only!)
    {
      short* cb = (tid < 128 ? h_hi : h_lo) + (size_t)((t + 2) & 3) * NB;
      int cr = (tid >> 3) & 15, cc = (tid & 7) << 3;
      st_sc1_b128(cb + (size_t)(rowbase + cr) * H + cg4 * 64 + cc, nanvec);
    }

    // ---- compute: 96 MFMA over the staged tile ----
    f32x4 acc[2][3];
#pragma unroll
    for (int a = 0; a < 2; ++a)
#pragma unroll
      for (int b = 0; b < 3; ++b) acc[a][b] = (f32x4){0.f, 0.f, 0.f, 0.f};
    const char* HB = (const char*)&Hh[t & 1][0];
    const char* LB = (const char*)&Hl[t & 1][0];
#pragma unroll
    for (int kk = 0; kk < 32; ++kk) {
      int ad = ((l15 * H + kk * 32 + kq8) * 2) ^ ((l15 & 7) << 4);
      s16x8 a_hi = *(const s16x8*)(HB + ad);
      s16x8 a_lo = *(const s16x8*)(LB + ad);
      int p = kk & 1;
      acc[p][0] = mfma_bf16(a_hi, whi[kk], acc[p][0]);
      acc[p][1] = mfma_bf16(a_lo, whi[kk], acc[p][1]);
      acc[p][2] = mfma_bf16(a_hi, wlo[kk], acc[p][2]);
    }
    f32x4 s = acc[0][0] + acc[0][1] + acc[0][2] + acc[1][0] + acc[1][1] + acc[1][2];

    // ---- epilogue: tanh, out stores, per-wave transpose, packed h stores --
    unsigned short hbv[4], lbv[4];
#pragma unroll
    for (int i = 0; i < 4; ++i) {
      float pre = s[i] + xp[i];
      float e = __expf(2.f * pre);
      float val = 1.f - 2.f / (e + 1.f);               // tanh
      out[offs[i]] = val;
      hbv[i] = f2bf(val);
      lbv[i] = f2bf(val - bf2f(hbv[i]));
      if (t == SEQ - 1)
        out[(size_t)M_TOTAL * H + (size_t)(rowbase + kq * 4 + i) * H + col] = val;
    }
    unsigned* tr = &TR[w][0][0];
#pragma unroll
    for (int i = 0; i < 4; ++i)
      tr[(kq * 4 + i) * 20 + l15] = (unsigned)hbv[i] | ((unsigned)lbv[i] << 16);
    asm volatile("s_waitcnt lgkmcnt(0)" ::: "memory");
    __builtin_amdgcn_sched_barrier(0);
    {
      int rrow = lane & 15, rhalf = (lane >> 4) & 1;
      uint4 wa = *(const uint4*)&tr[rrow * 20 + rhalf * 8];
      uint4 wb = *(const uint4*)&tr[rrow * 20 + rhalf * 8 + 4];
      unsigned o0, o1, o2, o3;
      if (lane < 32) {          // hi plane: low halves
        o0 = (wa.x & 0xFFFFu) | (wa.y << 16);
        o1 = (wa.z & 0xFFFFu) | (wa.w << 16);
        o2 = (wb.x & 0xFFFFu) | (wb.y << 16);
        o3 = (wb.z & 0xFFFFu) | (wb.w << 16);
      } else {                  // lo plane: high halves
        o0 = (wa.x >> 16) | (wa.y & 0xFFFF0000u);
        o1 = (wa.z >> 16) | (wa.w & 0xFFFF0000u);
        o2 = (wb.x >> 16) | (wb.y & 0xFFFF0000u);
        o3 = (wb.z >> 16) | (wb.w & 0xFFFF0000u);
      }
      uint4 pk4 = {o0, o1, o2, o3};
      short* plane = (lane < 32) ? h_hi : h_lo;
      short* dst = plane + (size_t)(t & 3) * NB
                 + (size_t)(rowbase + rrow) * H + colbase + rhalf * 8;
      st_sc1_b128(dst, __builtin_bit_cast(s16x8, pk4));
    }
#pragma unroll
    for (int i = 0; i < 4; ++i) { xp[i] = xpn[i]; offs[i] = offn[i]; }
  }
}

// ---------------- launch ---------------------------------------------------
extern "C" void kernel_launch(void* const* d_in, const int* in_sizes, int n_in,
                              void* d_out, int out_size, void* d_ws, size_t ws_size,
                              hipStream_t stream) {
  const float* x    = (const float*)d_in[0];
  const float* w_xh = (const float*)d_in[1];
  const float* b_xh = (const float*)d_in[2];
  const float* w_hh = (const float*)d_in[3];
  const float* b_hh = (const float*)d_in[4];
  const float* h0   = (const float*)d_in[5];
  float* out = (float*)d_out;
  char* ws = (char*)d_ws;

  short* wxT_hi = (short*)(ws + 0);            // 1,048,576
  short* wxT_lo = (short*)(ws + 1048576);      // 1,048,576
  short* whT_hi = (short*)(ws + 2097152);      // 2,097,152
  short* whT_lo = (short*)(ws + 4194304);      // 2,097,152
  short* h_hi   = (short*)(ws + 6291456);      // 4*64*1024*2 = 524,288
  short* h_lo   = (short*)(ws + 6815744);      // 524,288
  // total 7,340,032 bytes; no flags buffer (data-is-the-flag)

  conv_T<<<(DIN * H + 255) / 256, 256, 0, stream>>>(w_xh, DIN, H, wxT_hi, wxT_lo);
  conv_T<<<(H * H + 255) / 256, 256, 0, stream>>>(w_hh, H, H, whT_hi, whT_lo);
  init_h<<<(NBATCH * H) / 256, 256, 0, stream>>>(h0, h_hi, h_lo);

  proj_kernel<<<dim3(H / PBN, M_TOTAL / PBM), 256, 0, stream>>>(
      x, wxT_hi, wxT_lo, b_xh, b_hh, out);

  scan_kernel<<<64, 256, 0, stream>>>(whT_hi, whT_lo, out, h_hi, h_lo);
}

// Round 8
// 2856.203 us; speedup vs baseline: 1.3985x; 1.3985x over previous
//
#include <hip/hip_runtime.h>

#define DIN 512
#define H   1024
#define NBATCH 64
#define SEQ 512
#define M_TOTAL (NBATCH * SEQ)  // 32768

typedef float  f32x4  __attribute__((ext_vector_type(4)));
typedef __bf16 bf16x8 __attribute__((ext_vector_type(8)));
typedef short  s16x8  __attribute__((ext_vector_type(8)));
typedef short  s16x4  __attribute__((ext_vector_type(4)));

__device__ __forceinline__ unsigned short f2bf(float f) {
  unsigned u = __float_as_uint(f);
  u = (u + 0x7FFFu + ((u >> 16) & 1u)) >> 16;   // RNE truncate to bf16
  return (unsigned short)u;
}
__device__ __forceinline__ float bf2f(unsigned short h) {
  return __uint_as_float(((unsigned)h) << 16);
}
__device__ __forceinline__ f32x4 mfma_bf16(s16x8 a, s16x8 b, f32x4 c) {
  return __builtin_amdgcn_mfma_f32_16x16x32_bf16(
      __builtin_bit_cast(bf16x8, a), __builtin_bit_cast(bf16x8, b), c, 0, 0, 0);
}
// coherent (sc1) accesses: served at the die-level coherence point,
// no cache-maintenance side effects (proven R2/R4/R5)
__device__ __forceinline__ s16x8 ld_sc1_b128(const short* p) {
  s16x8 r;
  asm volatile("global_load_dwordx4 %0, %1, off sc1"
               : "=v"(r) : "v"(p) : "memory");
  return r;
}
__device__ __forceinline__ void st_sc1_b128(short* p, s16x8 v) {
  asm volatile("global_store_dwordx4 %0, %1, off sc1"
               :: "v"(p), "v"(v) : "memory");
}

// ---------------- prep: transpose + hi/lo bf16 convert --------------------
__global__ void conv_T(const float* __restrict__ in, int R, int C,
                       short* __restrict__ oh, short* __restrict__ ol) {
  int i = blockIdx.x * 256 + threadIdx.x;
  if (i >= R * C) return;
  int c = i / R, r = i - c * R;
  float v = in[r * C + c];
  unsigned short hb = f2bf(v);
  oh[i] = (short)hb;
  ol[i] = (short)f2bf(v - bf2f(hb));
}

// broadcast h0[1][H] into h-buffer slot 1 (read by scan step t=0)
__global__ void init_h(const float* __restrict__ h0,
                       short* __restrict__ h_hi, short* __restrict__ h_lo) {
  int i = blockIdx.x * 256 + threadIdx.x;      // 64*1024
  int c = i & (H - 1);
  float v = h0[c];
  unsigned short hb = f2bf(v);
  h_hi[NBATCH * H + i] = (short)hb;            // slot 1
  h_lo[NBATCH * H + i] = (short)f2bf(v - bf2f(hb));
}

// ---------------- projection GEMM: xp = x @ w_xh + b_xh + b_hh ------------
#define PBM 64
#define PBN 128
#define PBK 64
__global__ __launch_bounds__(256) void proj_kernel(
    const float* __restrict__ x,       // [M][DIN]
    const short* __restrict__ wT_hi,   // [H][DIN]
    const short* __restrict__ wT_lo,
    const float* __restrict__ b_xh,
    const float* __restrict__ b_hh,
    float* __restrict__ out) {         // [M][H] (d_out hidden region)
  __shared__ short Ahi[PBM * PBK], Alo[PBM * PBK];
  __shared__ short Bhi[PBN * PBK], Blo[PBN * PBK];
  const int n0 = blockIdx.x * PBN;
  const int m0 = blockIdx.y * PBM;
  const int tid = threadIdx.x;
  const int lane = tid & 63, w = tid >> 6;
  const int wr = w >> 1, wc = w & 1;
  const int l15 = lane & 15, kq8 = (lane >> 4) << 3;

  f32x4 acc[2][4];
#pragma unroll
  for (int a = 0; a < 2; ++a)
#pragma unroll
    for (int b = 0; b < 4; ++b) acc[a][b] = (f32x4){0.f, 0.f, 0.f, 0.f};

  for (int kc = 0; kc < DIN; kc += PBK) {
    {
      int r = tid >> 2, k0 = (tid & 3) << 4;
      const float* src = x + (size_t)(m0 + r) * DIN + kc + k0;
#pragma unroll
      for (int i = 0; i < 4; ++i) {
        float4 v = *(const float4*)(src + i * 4);
        unsigned short h0b = f2bf(v.x), h1b = f2bf(v.y), h2b = f2bf(v.z), h3b = f2bf(v.w);
        s16x4 hv = {(short)h0b, (short)h1b, (short)h2b, (short)h3b};
        s16x4 lv = {(short)f2bf(v.x - bf2f(h0b)), (short)f2bf(v.y - bf2f(h1b)),
                    (short)f2bf(v.z - bf2f(h2b)), (short)f2bf(v.w - bf2f(h3b))};
        int ad = (r * PBK + k0 + i * 4) * 2;
        ad ^= (r & 7) << 4;
        *(s16x4*)((char*)Ahi + ad) = hv;
        *(s16x4*)((char*)Alo + ad) = lv;
      }
    }
    {
      int c = tid >> 1, k0 = (tid & 1) << 5;
      const short* sh = wT_hi + (size_t)(n0 + c) * DIN + kc + k0;
      const short* sl = wT_lo + (size_t)(n0 + c) * DIN + kc + k0;
#pragma unroll
      for (int i = 0; i < 4; ++i) {
        s16x8 vh = *(const s16x8*)(sh + i * 8);
        s16x8 vl = *(const s16x8*)(sl + i * 8);
        int ad = (c * PBK + k0 + i * 8) * 2;
        ad ^= (c & 7) << 4;
        *(s16x8*)((char*)Bhi + ad) = vh;
        *(s16x8*)((char*)Blo + ad) = vl;
      }
    }
    __syncthreads();
#pragma unroll
    for (int ks = 0; ks < PBK; ks += 32) {
      s16x8 ah[2], al[2], bh[4], bl[4];
#pragma unroll
      for (int rt = 0; rt < 2; ++rt) {
        int row = wr * 32 + rt * 16 + l15;
        int ad = (row * PBK + ks + kq8) * 2;
        ad ^= (row & 7) << 4;
        ah[rt] = *(const s16x8*)((const char*)Ahi + ad);
        al[rt] = *(const s16x8*)((const char*)Alo + ad);
      }
#pragma unroll
      for (int ct = 0; ct < 4; ++ct) {
        int c = wc * 64 + ct * 16 + l15;
        int ad = (c * PBK + ks + kq8) * 2;
        ad ^= (c & 7) << 4;
        bh[ct] = *(const s16x8*)((const char*)Bhi + ad);
        bl[ct] = *(const s16x8*)((const char*)Blo + ad);
      }
#pragma unroll
      for (int rt = 0; rt < 2; ++rt)
#pragma unroll
        for (int ct = 0; ct < 4; ++ct) {
          acc[rt][ct] = mfma_bf16(ah[rt], bh[ct], acc[rt][ct]);
          acc[rt][ct] = mfma_bf16(al[rt], bh[ct], acc[rt][ct]);
          acc[rt][ct] = mfma_bf16(ah[rt], bl[ct], acc[rt][ct]);
        }
    }
    __syncthreads();
  }
#pragma unroll
  for (int rt = 0; rt < 2; ++rt)
#pragma unroll
    for (int ct = 0; ct < 4; ++ct) {
      int col = n0 + wc * 64 + ct * 16 + l15;
      float bias = b_xh[col] + b_hh[col];
#pragma unroll
      for (int i = 0; i < 4; ++i) {
        int m = m0 + wr * 32 + rt * 16 + ((lane >> 4) << 2) + i;
        out[(size_t)m * H + col] = acc[rt][ct][i] + bias;
      }
    }
}

// ---------------- persistent recurrent scan (v8 = proven R4 + R5 epilogue) -
// 64 blocks x 256 threads. bg = bid&3 (16 batch rows), cg4 = bid>>2 (64 cols;
// wave w owns 16). W hi+lo fragments in registers/AGPRs. Per step:
// poll 16 peer flags (sc1) -> bulk-stage h[16][1024] hi+lo -> LDS (16 b128
// sc1 loads in flight, XOR-swizzled) -> barrier -> 96 MFMA -> tanh ->
// per-wave LDS transpose -> ONE packed b128 sc1 h-store per lane (R5-proven)
// -> vmcnt(0) drain -> barrier -> 1 flag per block. No dispatch/residency
// assumptions (R4-proven protocol).
__global__ __launch_bounds__(256, 1) void scan_kernel(
    const short* __restrict__ whT_hi,  // [H][H]
    const short* __restrict__ whT_lo,
    float* __restrict__ out,           // d_out: [64][512][1024] then [64][1024]
    short* __restrict__ h_hi,          // [2][64][1024]
    short* __restrict__ h_lo,
    int* __restrict__ flags) {         // [4][512][16]
  __shared__ short Hhi[16 * H];        // 32 KB, XOR-swizzled
  __shared__ short Hlo[16 * H];        // 32 KB
  __shared__ unsigned TR[4][16][20];   // 5 KB per-wave transpose scratch
  const int tid = threadIdx.x;
  const int lane = tid & 63, w = tid >> 6;
  const int bid = blockIdx.x;
  const int bg = bid & 3, cg4 = bid >> 2;
  const int l15 = lane & 15, kq = lane >> 4, kq8 = kq << 3;
  const int colbase = cg4 * 64 + w * 16;
  const int col = colbase + l15;
  const int rowbase = bg * 16;
  const int NB = NBATCH * H;

  // W hi+lo fragments in registers/AGPRs: 64 x s16x8
  s16x8 whi[32], wlo[32];
#pragma unroll
  for (int kk = 0; kk < 32; ++kk) {
    whi[kk] = *(const s16x8*)(whT_hi + (size_t)col * H + kk * 32 + kq8);
    wlo[kk] = *(const s16x8*)(whT_lo + (size_t)col * H + kk * 32 + kq8);
  }

  // per-thread staging chunk offsets (constant across steps)
  int cbase[8];
#pragma unroll
  for (int j = 0; j < 8; ++j) {
    int c = j * 256 + tid;
    cbase[j] = (rowbase + (c >> 7)) * H + ((c & 127) << 3);
  }

  // xp prefetch for t=0 (no poll at t=0, off the critical path)
  float xp[4]; unsigned offs[4];
#pragma unroll
  for (int i = 0; i < 4; ++i) {
    int b = rowbase + kq * 4 + i;
    offs[i] = ((unsigned)b * SEQ + 0) * H + col;
    xp[i] = out[offs[i]];
  }

  for (int t = 0; t < SEQ; ++t) {
    const int prev = (t + 1) & 1, cur = t & 1;

    // ---- poll peers' flags for step t-1 ----
    if (t > 0) {
      const int* f = flags + ((bg * SEQ + (t - 1)) << 4);
      int spins = 0;
      while (true) {
        int v = 1;
        if (lane < 16)
          v = __hip_atomic_load(f + lane, __ATOMIC_RELAXED, __HIP_MEMORY_SCOPE_AGENT);
        if (__all(v != 0)) break;
        if (++spins > 20000) break;  // safety: wrong answer beats a hang
        __builtin_amdgcn_s_sleep(1);
      }
      __builtin_amdgcn_sched_barrier(0);
    }

    // ---- bulk stage h(t-1) -> LDS (16 b128 sc1 loads in flight) ----
    {
      const short* ghi = h_hi + (size_t)prev * NB;
      const short* glo = h_lo + (size_t)prev * NB;
      s16x8 sh[8], sl[8];
#pragma unroll
      for (int j = 0; j < 8; ++j) {
        sh[j] = ld_sc1_b128(ghi + cbase[j]);
        sl[j] = ld_sc1_b128(glo + cbase[j]);
      }
      asm volatile("s_waitcnt vmcnt(0)" ::: "memory");
      __builtin_amdgcn_sched_barrier(0);
#pragma unroll
      for (int j = 0; j < 8; ++j) {
        int c = j * 256 + tid;
        int ad = (c << 4) ^ (((c >> 7) & 7) << 4);   // XOR-swizzled
        *(s16x8*)((char*)Hhi + ad) = sh[j];
        *(s16x8*)((char*)Hlo + ad) = sl[j];
      }
    }
    __syncthreads();

    // xp prefetch for t+1: completes under MFMA, waited by epilogue drain
    float xpn[4] = {0.f, 0.f, 0.f, 0.f};
    unsigned offn[4] = {0u, 0u, 0u, 0u};
    if (t + 1 < SEQ) {
#pragma unroll
      for (int i = 0; i < 4; ++i) {
        int b = rowbase + kq * 4 + i;
        offn[i] = ((unsigned)b * SEQ + (t + 1)) * H + col;
        xpn[i] = out[offn[i]];
      }
    }

    // ---- compute: 96 MFMA over the staged tile ----
    f32x4 acc[2][3];
#pragma unroll
    for (int a = 0; a < 2; ++a)
#pragma unroll
      for (int b = 0; b < 3; ++b) acc[a][b] = (f32x4){0.f, 0.f, 0.f, 0.f};
#pragma unroll
    for (int kk = 0; kk < 32; ++kk) {
      int ad = ((l15 * H + kk * 32 + kq8) * 2) ^ ((l15 & 7) << 4);
      s16x8 a_hi = *(const s16x8*)((const char*)Hhi + ad);
      s16x8 a_lo = *(const s16x8*)((const char*)Hlo + ad);
      int p = kk & 1;
      acc[p][0] = mfma_bf16(a_hi, whi[kk], acc[p][0]);
      acc[p][1] = mfma_bf16(a_lo, whi[kk], acc[p][1]);
      acc[p][2] = mfma_bf16(a_hi, wlo[kk], acc[p][2]);
    }
    f32x4 s = acc[0][0] + acc[0][1] + acc[0][2] + acc[1][0] + acc[1][1] + acc[1][2];

    // ---- epilogue: tanh, out stores, per-wave transpose, packed h store --
    unsigned short hbv[4], lbv[4];
#pragma unroll
    for (int i = 0; i < 4; ++i) {
      float pre = s[i] + xp[i];
      float e = __expf(2.f * pre);
      float val = 1.f - 2.f / (e + 1.f);               // tanh
      out[offs[i]] = val;
      hbv[i] = f2bf(val);
      lbv[i] = f2bf(val - bf2f(hbv[i]));
      if (t == SEQ - 1)
        out[(size_t)M_TOTAL * H + (size_t)(rowbase + kq * 4 + i) * H + col] = val;
    }
    unsigned* tr = &TR[w][0][0];
#pragma unroll
    for (int i = 0; i < 4; ++i)
      tr[(kq * 4 + i) * 20 + l15] = (unsigned)hbv[i] | ((unsigned)lbv[i] << 16);
    asm volatile("s_waitcnt lgkmcnt(0)" ::: "memory");
    __builtin_amdgcn_sched_barrier(0);
    {
      int rrow = lane & 15, rhalf = (lane >> 4) & 1;
      const unsigned* src = &tr[rrow * 20 + rhalf * 8];
      uint4 wa = *(const uint4*)(src);
      uint4 wb = *(const uint4*)(src + 4);
      unsigned o0, o1, o2, o3;
      if (lane < 32) {          // hi plane: low halves
        o0 = (wa.x & 0xFFFFu) | (wa.y << 16);
        o1 = (wa.z & 0xFFFFu) | (wa.w << 16);
        o2 = (wb.x & 0xFFFFu) | (wb.y << 16);
        o3 = (wb.z & 0xFFFFu) | (wb.w << 16);
      } else {                  // lo plane: high halves
        o0 = (wa.x >> 16) | (wa.y & 0xFFFF0000u);
        o1 = (wa.z >> 16) | (wa.w & 0xFFFF0000u);
        o2 = (wb.x >> 16) | (wb.y & 0xFFFF0000u);
        o3 = (wb.z >> 16) | (wb.w & 0xFFFF0000u);
      }
      uint4 pk4 = {o0, o1, o2, o3};
      short* plane = (lane < 32) ? h_hi : h_lo;
      short* dst = plane + (size_t)cur * NB
                 + (size_t)(rowbase + rrow) * H + colbase + rhalf * 8;
      st_sc1_b128(dst, __builtin_bit_cast(s16x8, pk4));
    }
    // release: drain h stores (sc1 acks = coherence-point visible), barrier,
    // one flag per block
    asm volatile("s_waitcnt vmcnt(0)" ::: "memory");
    __syncthreads();
    if (tid == 0)
      __hip_atomic_store(&flags[((bg * SEQ + t) << 4) + cg4], 1,
                         __ATOMIC_RELAXED, __HIP_MEMORY_SCOPE_AGENT);

#pragma unroll
    for (int i = 0; i < 4; ++i) { xp[i] = xpn[i]; offs[i] = offn[i]; }
  }
}

// ---------------- launch ---------------------------------------------------
extern "C" void kernel_launch(void* const* d_in, const int* in_sizes, int n_in,
                              void* d_out, int out_size, void* d_ws, size_t ws_size,
                              hipStream_t stream) {
  const float* x    = (const float*)d_in[0];
  const float* w_xh = (const float*)d_in[1];
  const float* b_xh = (const float*)d_in[2];
  const float* w_hh = (const float*)d_in[3];
  const float* b_hh = (const float*)d_in[4];
  const float* h0   = (const float*)d_in[5];
  float* out = (float*)d_out;
  char* ws = (char*)d_ws;

  short* wxT_hi = (short*)(ws + 0);            // 1,048,576
  short* wxT_lo = (short*)(ws + 1048576);      // 1,048,576
  short* whT_hi = (short*)(ws + 2097152);      // 2,097,152
  short* whT_lo = (short*)(ws + 4194304);      // 2,097,152
  short* h_hi   = (short*)(ws + 6291456);      // 2*64*1024*2 = 262,144
  short* h_lo   = (short*)(ws + 6553600);      // 262,144
  int*   flags  = (int*)  (ws + 6815744);      // 4*512*16*4 = 131,072
  // total 6,946,816 bytes

  hipMemsetAsync(ws + 6815744, 0, 131072, stream);  // reset sync flags each call

  conv_T<<<(DIN * H + 255) / 256, 256, 0, stream>>>(w_xh, DIN, H, wxT_hi, wxT_lo);
  conv_T<<<(H * H + 255) / 256, 256, 0, stream>>>(w_hh, H, H, whT_hi, whT_lo);
  init_h<<<(NBATCH * H) / 256, 256, 0, stream>>>(h0, h_hi, h_lo);

  proj_kernel<<<dim3(H / PBN, M_TOTAL / PBM), 256, 0, stream>>>(
      x, wxT_hi, wxT_lo, b_xh, b_hh, out);

  scan_kernel<<<64, 256, 0, stream>>>(whT_hi, whT_lo, out, h_hi, h_lo, flags);
}